// Round 2
// baseline (376.446 us; speedup 1.0000x reference)
//
#include <hip/hip_runtime.h>
#include <stdint.h>

#define BLOCK 256
#define ITEMS 8
#define TILE (BLOCK * ITEMS)   // 2048 elements per block
#define WPB (TILE / 64)        // 32 bitmask words per block
#define MAXSEG 64
#define CHUNK 64               // tiles per count-chunk (for per-block self-scan)
#define NCMAX 257              // supports nb <= 16384 (n <= 33.5M)
#define THRESH 0.1f

typedef unsigned long long u64;

__device__ __forceinline__ int find_seg(const int* rs, int n_seg, int i) {
    // largest s with rs[s] <= i
    int lo = 0, hi = n_seg;
    while (hi - lo > 1) {
        int mid = (lo + hi) >> 1;
        if (rs[mid] <= i) lo = mid; else hi = mid;
    }
    return lo;
}

// Wave-cooperative global keep-prefix at element index idx.
// prefix = chq[chunk] (exclusive chunk prefix, LDS) + counts of tiles before
// idx's tile within the chunk (<=63 loads) + popcounts of this tile's words
// before idx (<=31 loads) + partial word. Result valid on lane 0.
__device__ __forceinline__ int wave_prefix_at(int idx, const int* chq,
        const int* __restrict__ bc, const u64* __restrict__ bm, int lane) {
    int t = idx / TILE;
    int c = t / CHUNK;
    int v = 0;
    int j = c * CHUNK + lane;
    if (j < t) v += bc[j];
    int wq = idx >> 6;
    int w = t * WPB + lane;
    if (lane < WPB && w < wq) v += __popcll(bm[w]);
    if (lane == 0 && (idx & 63)) v += __popcll(bm[wq] & ((1ull << (idx & 63)) - 1));
    for (int o = 32; o > 0; o >>= 1) v += __shfl_down(v, o, 64);
    return chq[c] + v;
}

// Pass 1 (fused pass1 + segfix): single read of score producing
//   - threshold keep-bitmask (s > THRESH)
//   - per-block keep counts + per-chunk count sums (chunk_sums, -1-encoded)
//   - per-block packed (min_bits<<32 | idx) partials, <=2 segments per block
//   - global per-segment min via device-scope atomicMin on seg_packed
// Then each block arrives at its segment(s)' counter (init -1); the LAST
// arriver per segment performs the min-tie bitmask/count fixup in-kernel
// (replaces the old k_segfix dispatch; overlaps the pass-1 tail).
__global__ __launch_bounds__(BLOCK) void k_pass1(const float* __restrict__ score,
        const int* __restrict__ row_splits, int n_seg, int n, int nwords,
        u64* __restrict__ partial_val, int* __restrict__ partial_seg,
        u64* __restrict__ bitmask, int* __restrict__ block_counts,
        u64* __restrict__ seg_packed, int* __restrict__ seg_ctr,
        int* __restrict__ chunk_sums) {
    __shared__ int rs[MAXSEG + 1];
    __shared__ u64 wval[8];
    __shared__ int wseg[8];
    __shared__ int wsum[4];
    __shared__ int sfix[2];
    __shared__ u64 sminp;
    __shared__ int nmatch;
    __shared__ int mlist[64];
    for (int j = threadIdx.x; j <= n_seg; j += BLOCK) rs[j] = row_splits[j];
    __syncthreads();
    int lane = threadIdx.x & 63, wv = threadIdx.x >> 6;
    int wbase = blockIdx.x * TILE + wv * 512;
    u64 m0 = ~0ull, m1 = ~0ull;
    int sf = -1, sl = -1, cnt = 0;
    if (wbase < n) {   // wave-uniform
        int wend = min(n, wbase + 512) - 1;
        sf = find_seg(rs, n_seg, wbase);
        sl = find_seg(rs, n_seg, wend);
        int bval = (sl != sf) ? rs[sf + 1] : 0x7FFFFFFF;
        int tbase = wbase + lane * 8;
        unsigned int kbyte = 0;
        if (tbase < n) {
            float v[8];
            if (tbase + 8 <= n) {
                float4 f0 = *(const float4*)(score + tbase);
                float4 f1 = *(const float4*)(score + tbase + 4);
                v[0]=f0.x; v[1]=f0.y; v[2]=f0.z; v[3]=f0.w;
                v[4]=f1.x; v[5]=f1.y; v[6]=f1.z; v[7]=f1.w;
            } else {
                for (int j = 0; j < 8; j++) v[j] = (tbase + j < n) ? score[tbase + j] : 1.0f;
            }
            #pragma unroll
            for (int j = 0; j < 8; j++) {
                int i = tbase + j;
                if (i < n) {
                    u64 p = ((u64)__float_as_uint(v[j]) << 32) | (unsigned int)i;
                    if (i < bval) m0 = min(m0, p); else m1 = min(m1, p);
                    if (v[j] > THRESH) kbyte |= 1u << j;
                }
            }
            cnt = __popc(kbyte);
        }
        // assemble 64-bit words within groups of 8 lanes
        u64 acc = ((u64)kbyte) << (8 * (lane & 7));
        acc |= __shfl_xor((unsigned long long)acc, 1, 64);
        acc |= __shfl_xor((unsigned long long)acc, 2, 64);
        acc |= __shfl_xor((unsigned long long)acc, 4, 64);
        int src = (lane < 8) ? (8 * lane) : lane;
        u64 myword = __shfl((unsigned long long)acc, src, 64);
        for (int o = 32; o > 0; o >>= 1) {
            m0 = min(m0, (u64)__shfl_down((unsigned long long)m0, o, 64));
            m1 = min(m1, (u64)__shfl_down((unsigned long long)m1, o, 64));
            cnt += __shfl_down(cnt, o, 64);
        }
        if (lane < 8) {
            int w = (wbase >> 6) + lane;
            if (w < nwords) bitmask[w] = myword;
        }
    }
    if (lane == 0) {
        wval[2 * wv] = m0;     wseg[2 * wv] = sf;
        wval[2 * wv + 1] = m1; wseg[2 * wv + 1] = (sl != sf) ? sl : -1;
        wsum[wv] = (wbase < n) ? cnt : 0;
    }
    __syncthreads();
    if (threadIdx.x == 0) {
        int base = blockIdx.x * TILE;
        int endi = min(n, base + TILE) - 1;
        int s0 = find_seg(rs, n_seg, base);
        int s1 = find_seg(rs, n_seg, endi);
        u64 o0 = ~0ull, o1 = ~0ull;
        for (int k = 0; k < 8; k++) {
            if (wseg[k] == s0) o0 = min(o0, wval[k]);
            else if (wseg[k] == s1) o1 = min(o1, wval[k]);
        }
        partial_val[2 * blockIdx.x] = o0;
        partial_seg[2 * blockIdx.x] = s0;
        partial_val[2 * blockIdx.x + 1] = o1;
        partial_seg[2 * blockIdx.x + 1] = (s1 != s0) ? s1 : -1;
        int bc = wsum[0] + wsum[1] + wsum[2] + wsum[3];
        block_counts[blockIdx.x] = bc;
        // global segment min + chunk count accumulation (device-scope)
        atomicMin(&seg_packed[s0], o0);
        if (s1 != s0) atomicMin(&seg_packed[s1], o1);
        atomicAdd(&chunk_sums[blockIdx.x / CHUNK], bc);
        // publish plain stores (partials/bitmask drained by prior barrier's
        // vmcnt(0); this fence writes back this XCD's L2 device-wide) and
        // order the atomics above before the arrival below.
        __threadfence();
        int f0 = -1, f1 = -1;
        {
            int nblk = (rs[s0 + 1] - 1) / TILE - rs[s0] / TILE + 1;
            if (atomicAdd(&seg_ctr[s0], 1) == nblk - 2) f0 = s0;   // ctr init -1
        }
        if (s1 != s0) {
            int nblk = (rs[s1 + 1] - 1) / TILE - rs[s1] / TILE + 1;
            if (atomicAdd(&seg_ctr[s1], 1) == nblk - 2) f1 = s1;
        }
        if (f0 >= 0 || f1 >= 0) __threadfence();   // acquire: peers' data visible
        sfix[0] = f0; sfix[1] = f1;
    }
    __syncthreads();
    // last arriver per segment performs min-tie fixup (old k_segfix body).
    // sfix is block-uniform, so branches/syncthreads below are uniform.
    for (int k = 0; k < 2; k++) {
        int s = sfix[k];
        if (s < 0) continue;
        if (threadIdx.x == 0) { sminp = seg_packed[s]; nmatch = 0; }
        __syncthreads();
        u64 sp = sminp;
        if (sp != ~0ull) {
            unsigned int smb = (unsigned int)(sp >> 32);
            if (__uint_as_float(smb) <= THRESH) {
                int lo = rs[s], hi = rs[s + 1];
                int e0 = 2 * (lo / TILE), e1 = 2 * ((hi - 1) / TILE) + 1;
                for (int e = e0 + threadIdx.x; e <= e1; e += BLOCK)
                    if (partial_seg[e] == s && (unsigned int)(partial_val[e] >> 32) == smb) {
                        int kk = atomicAdd(&nmatch, 1);   // LDS atomic, rare
                        if (kk < 64) mlist[kk] = e >> 1;
                    }
                __syncthreads();
                int nm = min(nmatch, 64);
                for (int kk = 0; kk < nm; kk++) {
                    int b = mlist[kk];
                    int rlo = max(b * TILE, lo);
                    int rhi = min(min((b + 1) * TILE, n), hi);
                    int c = 0;
                    for (int i = rlo + threadIdx.x; i < rhi; i += BLOCK) {
                        if (__float_as_uint(score[i]) == smb) {
                            atomicOr(&bitmask[i >> 6], 1ull << (i & 63));
                            c++;
                        }
                    }
                    for (int o = 32; o > 0; o >>= 1) c += __shfl_down(c, o, 64);
                    if (lane == 0 && c) {
                        atomicAdd(&block_counts[b], c);
                        atomicAdd(&chunk_sums[b / CHUNK], c);
                    }
                }
            }
        }
        __syncthreads();
    }
}

// Pass 2 (fused scanq + output): each block derives its own global offset,
// its segments' rep positions, and any newrs boundary it owns, via
// wave-cooperative prefix queries over chunk_sums/block_counts/bitmask
// (all L2-resident; replaces the single-block k_scanq dispatch). Then the
// original output body: back values in registers for 4 phase-aligned
// positions -> dwordx4 stores; sel indices staged in LDS with slot offset so
// vector reads are aligned ds_read_b128. Assumes <=1 segment boundary per
// 2048-elem block (seg len >> 2048 here) and nchunk <= NCMAX.
__global__ __launch_bounds__(BLOCK) void k_output(const int* __restrict__ row_splits,
        int n_seg, int n, int nb, int nchunk, int M,
        const u64* __restrict__ seg_packed, const u64* __restrict__ bitmask,
        const int* __restrict__ block_counts, const int* __restrict__ chunk_sums,
        int* __restrict__ sel_out, int* __restrict__ back_out,
        int* __restrict__ newrs_out) {
    __shared__ int rs[MAXSEG + 1];
    __shared__ u64 swords[WPB];
    __shared__ int wpre[WPB];
    __shared__ int shead[8];   // bval, s0, s1, tot, bo, rep0, rep1
    __shared__ int chq[NCMAX];
    __shared__ alignas(16) int skel[TILE + 8];
    for (int j = threadIdx.x; j <= n_seg; j += BLOCK) rs[j] = row_splits[j];
    for (int t = threadIdx.x; t < nchunk; t += BLOCK) chq[t] = chunk_sums[t] + 1; // decode -1 init
    int base = blockIdx.x * TILE;
    int lim = min(TILE, n - base);
    int nw = (lim + 63) >> 6;
    for (int j = threadIdx.x; j < nw; j += BLOCK) swords[j] = bitmask[(base >> 6) + j];
    __syncthreads();
    if (threadIdx.x == 0) {
        int acc = 0;
        for (int k = 0; k < nw; k++) { wpre[k] = acc; acc += __popcll(swords[k]); }
        int s0 = find_seg(rs, n_seg, base);
        int s1 = find_seg(rs, n_seg, base + lim - 1);
        shead[0] = (s1 != s0) ? rs[s0 + 1] : 0x7FFFFFFF;
        shead[1] = s0;
        shead[2] = s1;
        shead[3] = acc;
        int a2 = 0;   // exclusive chunk prefix (serial over <=NCMAX entries)
        for (int c = 0; c < nchunk; c++) { int t = chq[c]; chq[c] = a2; a2 += t; }
    }
    __syncthreads();
    int lane = threadIdx.x & 63, wv = threadIdx.x >> 6;
    {
        int s0 = shead[1], s1 = shead[2];
        if (wv == 0) {
            int r = wave_prefix_at(base, chq, block_counts, bitmask, lane);
            if (lane == 0) shead[4] = r;                       // block offset
        } else if (wv == 1) {
            unsigned int u = (unsigned int)(seg_packed[s0] & 0xFFFFFFFFu);
            int r = (u >= (unsigned int)n) ? M
                    : wave_prefix_at((int)u, chq, block_counts, bitmask, lane);
            if (lane == 0) shead[5] = r;                       // rep0
        } else if (wv == 2) {
            unsigned int u = (unsigned int)(seg_packed[s1] & 0xFFFFFFFFu);
            int r = (u >= (unsigned int)n) ? M
                    : wave_prefix_at((int)u, chq, block_counts, bitmask, lane);
            if (lane == 0) shead[6] = r;                       // rep1
        } else {
            // newrs boundaries owned by this block (each rs[q] < n lies in
            // exactly one block's range); q = n_seg handled by last block.
            for (int q = 0; q < n_seg; q++) {
                int u = rs[q];
                if (u >= base && u < base + lim) {
                    int r = wave_prefix_at(u, chq, block_counts, bitmask, lane);
                    if (lane == 0) newrs_out[q] = r;
                }
            }
            if (blockIdx.x == nb - 1 && lane == 0) newrs_out[n_seg] = M;
        }
    }
    __syncthreads();
    int bval = shead[0], tot = shead[3], bo = shead[4];
    int rep0 = shead[5], rep1 = shead[6];
    // phases
    int st_b = (int)((4 - ((((uintptr_t)(back_out + base)) >> 2) & 3)) & 3);
    if (st_b > lim) st_b = lim;
    int st_s = (int)((4 - ((((uintptr_t)(sel_out + bo)) >> 2) & 3)) & 3);
    if (st_s > tot) st_s = tot;
    int selpad = 4 - st_s;          // skel slot = (pos - bo) + selpad; first aligned slot = 4

    // main: full int4 groups of back_out; also stage kept indices into skel
    int ngroups = (lim - st_b) >> 2;
    for (int g = threadIdx.x; g < ngroups; g += BLOCK) {
        int j0 = st_b + 4 * g;
        int vals[4];
        #pragma unroll
        for (int k = 0; k < 4; k++) {
            int j = j0 + k;
            int widx = j >> 6, r = j & 63;
            u64 w = swords[widx];
            int i = base + j;
            if ((w >> r) & 1) {
                int pos = bo + wpre[widx] + __popcll(w & ((1ull << r) - 1));
                vals[k] = pos;
                skel[pos - bo + selpad] = i;
            } else {
                vals[k] = (i >= bval) ? rep1 : rep0;
            }
        }
        *(int4*)(back_out + base + j0) = make_int4(vals[0], vals[1], vals[2], vals[3]);
    }
    // edges of back region (<=3 head, <=3 tail)
    for (int j = threadIdx.x; j < st_b; j += BLOCK) {
        int widx = j >> 6, r = j & 63;
        u64 w = swords[widx];
        int i = base + j, val;
        if ((w >> r) & 1) {
            int pos = bo + wpre[widx] + __popcll(w & ((1ull << r) - 1));
            val = pos;
            skel[pos - bo + selpad] = i;
        } else val = (i >= bval) ? rep1 : rep0;
        back_out[i] = val;
    }
    for (int j = st_b + 4 * ngroups + threadIdx.x; j < lim; j += BLOCK) {
        int widx = j >> 6, r = j & 63;
        u64 w = swords[widx];
        int i = base + j, val;
        if ((w >> r) & 1) {
            int pos = bo + wpre[widx] + __popcll(w & ((1ull << r) - 1));
            val = pos;
            skel[pos - bo + selpad] = i;
        } else val = (i >= bval) ? rep1 : rep0;
        back_out[i] = val;
    }
    __syncthreads();
    // sel_out: aligned int4 stores fed by aligned ds_read_b128
    int nvg = (tot - st_s) >> 2;
    for (int g = threadIdx.x; g < nvg; g += BLOCK) {
        int4 v = *(const int4*)&skel[4 + 4 * g];
        *(int4*)(sel_out + bo + st_s + 4 * g) = v;
    }
    for (int j = threadIdx.x; j < st_s; j += BLOCK) sel_out[bo + j] = skel[j + selpad];
    for (int j = st_s + 4 * nvg + threadIdx.x; j < tot; j += BLOCK) sel_out[bo + j] = skel[j + selpad];
}

extern "C" void kernel_launch(void* const* d_in, const int* in_sizes, int n_in,
                              void* d_out, int out_size, void* d_ws, size_t ws_size,
                              hipStream_t stream) {
    const float* score = (const float*)d_in[0];
    const int* row_splits = (const int*)d_in[1];
    int n = in_sizes[0];
    int n_seg = in_sizes[1] - 1;
    int M = out_size - (n_seg + 1) - n;
    int nb = (n + TILE - 1) / TILE;
    int nwords = (n + 63) / 64;
    int nchunk = (nb + CHUNK - 1) / CHUNK;

    u64* seg_packed   = (u64*)d_ws;                      // MAXSEG u64  (init 0xFF)
    int* seg_ctr      = (int*)(seg_packed + MAXSEG);     // MAXSEG int  (init -1)
    int* chunk_sums   = seg_ctr + MAXSEG;                // nchunk int  (init -1)
    uintptr_t pv_addr = (uintptr_t)(chunk_sums + nchunk);
    pv_addr = (pv_addr + 7) & ~(uintptr_t)7;
    u64* partial_val  = (u64*)pv_addr;                   // 2*nb u64
    int* partial_seg  = (int*)(partial_val + 2 * nb);    // 2*nb int
    int* block_counts = partial_seg + 2 * nb;            // nb int
    uintptr_t bm_addr = (uintptr_t)(block_counts + nb);
    bm_addr = (bm_addr + 7) & ~(uintptr_t)7;
    u64* bitmask      = (u64*)bm_addr;                   // nwords u64

    int* out = (int*)d_out;
    int* sel_out   = out;
    int* newrs_out = out + M;
    int* back_out  = out + M + (n_seg + 1);

    // single tiny init: seg_packed=~0 (atomicMin identity), seg_ctr=-1
    // (arrival counters), chunk_sums=-1 (-1-encoded accumulators)
    size_t init_bytes = (size_t)((char*)(chunk_sums + nchunk) - (char*)d_ws);
    hipMemsetAsync(d_ws, 0xFF, init_bytes, stream);
    hipLaunchKernelGGL(k_pass1, dim3(nb), dim3(BLOCK), 0, stream,
                       score, row_splits, n_seg, n, nwords,
                       partial_val, partial_seg, bitmask, block_counts,
                       seg_packed, seg_ctr, chunk_sums);
    hipLaunchKernelGGL(k_output, dim3(nb), dim3(BLOCK), 0, stream,
                       row_splits, n_seg, n, nb, nchunk, M,
                       seg_packed, bitmask, block_counts, chunk_sums,
                       sel_out, back_out, newrs_out);
}

// Round 3
// 205.584 us; speedup vs baseline: 1.8311x; 1.8311x over previous
//
#include <hip/hip_runtime.h>
#include <stdint.h>

#define BLOCK 256
#define ITEMS 8
#define TILE (BLOCK * ITEMS)   // 2048 elements per block
#define WPB (TILE / 64)        // 32 bitmask words per block
#define MAXSEG 64
#define CHUNK 64               // tiles per count-chunk (for per-block self-scan)
#define NCMAX 257              // supports nb <= 16384 (n <= 33.5M)
#define THRESH 0.1f

typedef unsigned long long u64;

__device__ __forceinline__ int find_seg(const int* rs, int n_seg, int i) {
    // largest s with rs[s] <= i
    int lo = 0, hi = n_seg;
    while (hi - lo > 1) {
        int mid = (lo + hi) >> 1;
        if (rs[mid] <= i) lo = mid; else hi = mid;
    }
    return lo;
}

// Wave-cooperative global keep-prefix at element index idx.
// prefix = chq[chunk] (exclusive chunk prefix, LDS) + counts of tiles before
// idx's tile within the chunk (<=63 loads) + popcounts of this tile's words
// before idx (<=31 loads) + partial word. Result valid on lane 0.
__device__ __forceinline__ int wave_prefix_at(int idx, const int* chq,
        const int* __restrict__ bc, const u64* __restrict__ bm, int lane) {
    int t = idx / TILE;
    int c = t / CHUNK;
    int v = 0;
    int j = c * CHUNK + lane;
    if (j < t) v += bc[j];
    int wq = idx >> 6;
    int w = t * WPB + lane;
    if (lane < WPB && w < wq) v += __popcll(bm[w]);
    if (lane == 0 && (idx & 63)) v += __popcll(bm[wq] & ((1ull << (idx & 63)) - 1));
    for (int o = 32; o > 0; o >>= 1) v += __shfl_down(v, o, 64);
    return chq[c] + v;
}

// Pass 1: single read of score producing
//   - threshold keep-bitmask (s > THRESH)  [min-tied bits fixed up in k_segfix]
//   - per-block keep counts + per-chunk sums (chunk_sums, -1-encoded, atomic)
//   - per-block packed (min_bits<<32 | idx) partials, <=2 segments per block
//   - per-segment global min via device-scope atomicMin (coherent; NO fences —
//     the Round-1 per-block __threadfence was an agent-scope L2 writeback per
//     block and cost ~200 us of stall; all cross-block plain-store visibility
//     is now carried by kernel boundaries only)
__global__ __launch_bounds__(BLOCK) void k_pass1(const float* __restrict__ score,
        const int* __restrict__ row_splits, int n_seg, int n, int nwords,
        u64* __restrict__ partial_val, int* __restrict__ partial_seg,
        u64* __restrict__ bitmask, int* __restrict__ block_counts,
        u64* __restrict__ seg_packed, int* __restrict__ chunk_sums) {
    __shared__ int rs[MAXSEG + 1];
    __shared__ u64 wval[8];
    __shared__ int wseg[8];
    __shared__ int wsum[4];
    for (int j = threadIdx.x; j <= n_seg; j += BLOCK) rs[j] = row_splits[j];
    __syncthreads();
    int lane = threadIdx.x & 63, wv = threadIdx.x >> 6;
    int wbase = blockIdx.x * TILE + wv * 512;
    u64 m0 = ~0ull, m1 = ~0ull;
    int sf = -1, sl = -1, cnt = 0;
    if (wbase < n) {   // wave-uniform
        int wend = min(n, wbase + 512) - 1;
        sf = find_seg(rs, n_seg, wbase);
        sl = find_seg(rs, n_seg, wend);
        int bval = (sl != sf) ? rs[sf + 1] : 0x7FFFFFFF;
        int tbase = wbase + lane * 8;
        unsigned int kbyte = 0;
        if (tbase < n) {
            float v[8];
            if (tbase + 8 <= n) {
                float4 f0 = *(const float4*)(score + tbase);
                float4 f1 = *(const float4*)(score + tbase + 4);
                v[0]=f0.x; v[1]=f0.y; v[2]=f0.z; v[3]=f0.w;
                v[4]=f1.x; v[5]=f1.y; v[6]=f1.z; v[7]=f1.w;
            } else {
                for (int j = 0; j < 8; j++) v[j] = (tbase + j < n) ? score[tbase + j] : 1.0f;
            }
            #pragma unroll
            for (int j = 0; j < 8; j++) {
                int i = tbase + j;
                if (i < n) {
                    u64 p = ((u64)__float_as_uint(v[j]) << 32) | (unsigned int)i;
                    if (i < bval) m0 = min(m0, p); else m1 = min(m1, p);
                    if (v[j] > THRESH) kbyte |= 1u << j;
                }
            }
            cnt = __popc(kbyte);
        }
        // assemble 64-bit words within groups of 8 lanes
        u64 acc = ((u64)kbyte) << (8 * (lane & 7));
        acc |= __shfl_xor((unsigned long long)acc, 1, 64);
        acc |= __shfl_xor((unsigned long long)acc, 2, 64);
        acc |= __shfl_xor((unsigned long long)acc, 4, 64);
        int src = (lane < 8) ? (8 * lane) : lane;
        u64 myword = __shfl((unsigned long long)acc, src, 64);
        for (int o = 32; o > 0; o >>= 1) {
            m0 = min(m0, (u64)__shfl_down((unsigned long long)m0, o, 64));
            m1 = min(m1, (u64)__shfl_down((unsigned long long)m1, o, 64));
            cnt += __shfl_down(cnt, o, 64);
        }
        if (lane < 8) {
            int w = (wbase >> 6) + lane;
            if (w < nwords) bitmask[w] = myword;
        }
    }
    if (lane == 0) {
        wval[2 * wv] = m0;     wseg[2 * wv] = sf;
        wval[2 * wv + 1] = m1; wseg[2 * wv + 1] = (sl != sf) ? sl : -1;
        wsum[wv] = (wbase < n) ? cnt : 0;
    }
    __syncthreads();
    if (threadIdx.x == 0) {
        int base = blockIdx.x * TILE;
        int endi = min(n, base + TILE) - 1;
        int s0 = find_seg(rs, n_seg, base);
        int s1 = find_seg(rs, n_seg, endi);
        u64 o0 = ~0ull, o1 = ~0ull;
        for (int k = 0; k < 8; k++) {
            if (wseg[k] == s0) o0 = min(o0, wval[k]);
            else if (wseg[k] == s1) o1 = min(o1, wval[k]);
        }
        partial_val[2 * blockIdx.x] = o0;
        partial_seg[2 * blockIdx.x] = s0;
        partial_val[2 * blockIdx.x + 1] = o1;
        partial_seg[2 * blockIdx.x + 1] = (s1 != s0) ? s1 : -1;
        int bc = wsum[0] + wsum[1] + wsum[2] + wsum[3];
        block_counts[blockIdx.x] = bc;
        // coherent device-scope atomics only (no fences)
        atomicMin(&seg_packed[s0], o0);
        if (s1 != s0) atomicMin(&seg_packed[s1], o1);
        atomicAdd(&chunk_sums[blockIdx.x / CHUNK], bc);
    }
}

// Pass 2: one block PER SEGMENT. seg min is already reduced in seg_packed
// (pass1's atomicMin; visible across the kernel boundary). If segmin <= THRESH,
// set keep bits for min-tied elements (re-reads only the matched ~2048-elem
// tiles) and bump block_counts + chunk_sums.
__global__ __launch_bounds__(BLOCK) void k_segfix(const float* __restrict__ score,
        const int* __restrict__ row_splits, int n,
        const u64* __restrict__ partial_val, const int* __restrict__ partial_seg,
        const u64* __restrict__ seg_packed, u64* __restrict__ bitmask,
        int* __restrict__ block_counts, int* __restrict__ chunk_sums) {
    __shared__ int nmatch;
    __shared__ int mlist[64];
    int s = blockIdx.x;
    int lo = row_splits[s], hi = row_splits[s + 1];
    int lane = threadIdx.x & 63;
    if (threadIdx.x == 0) nmatch = 0;
    __syncthreads();
    if (hi <= lo) return;
    u64 sp = seg_packed[s];
    if (sp == ~0ull) return;
    unsigned int smb = (unsigned int)(sp >> 32);
    if (__uint_as_float(smb) > THRESH) return;   // threshold bit already covers min elems
    int e0 = 2 * (lo / TILE);
    int e1 = 2 * ((hi - 1) / TILE) + 1;
    for (int e = e0 + threadIdx.x; e <= e1; e += BLOCK) {
        if (partial_seg[e] == s && (unsigned int)(partial_val[e] >> 32) == smb) {
            int k = atomicAdd(&nmatch, 1);   // LDS atomic, rare
            if (k < 64) mlist[k] = e >> 1;
        }
    }
    __syncthreads();
    int nm = min(nmatch, 64);
    for (int k = 0; k < nm; k++) {
        int b = mlist[k];
        int rlo = max(b * TILE, lo);
        int rhi = min(min((b + 1) * TILE, n), hi);
        int c = 0;
        for (int i = rlo + threadIdx.x; i < rhi; i += BLOCK) {
            if (__float_as_uint(score[i]) == smb) {
                atomicOr(&bitmask[i >> 6], 1ull << (i & 63));
                c++;
            }
        }
        for (int o = 32; o > 0; o >>= 1) c += __shfl_down(c, o, 64);
        if (lane == 0 && c) {
            atomicAdd(&block_counts[b], c);
            atomicAdd(&chunk_sums[b / CHUNK], c);
        }
    }
}

// Pass 3 (fused scanq + output): each block derives its own global offset,
// its segments' rep positions, and any newrs boundary it owns, via
// wave-cooperative prefix queries over chunk_sums/block_counts/bitmask
// (all L2-resident; replaces the old single-block k_scanq dispatch). Then the
// output body: back values in registers for 4 phase-aligned positions ->
// dwordx4 stores; sel indices staged in LDS with slot offset so vector reads
// are aligned ds_read_b128. Assumes <=1 segment boundary per 2048-elem block
// (seg len >> 2048 here) and nchunk <= NCMAX.
__global__ __launch_bounds__(BLOCK) void k_output(const int* __restrict__ row_splits,
        int n_seg, int n, int nb, int nchunk, int M,
        const u64* __restrict__ seg_packed, const u64* __restrict__ bitmask,
        const int* __restrict__ block_counts, const int* __restrict__ chunk_sums,
        int* __restrict__ sel_out, int* __restrict__ back_out,
        int* __restrict__ newrs_out) {
    __shared__ int rs[MAXSEG + 1];
    __shared__ u64 swords[WPB];
    __shared__ int wpre[WPB];
    __shared__ int shead[8];   // bval, s0, s1, tot, bo, rep0, rep1
    __shared__ int chq[NCMAX];
    __shared__ alignas(16) int skel[TILE + 8];
    for (int j = threadIdx.x; j <= n_seg; j += BLOCK) rs[j] = row_splits[j];
    for (int t = threadIdx.x; t < nchunk; t += BLOCK) chq[t] = chunk_sums[t] + 1; // decode -1 init
    int base = blockIdx.x * TILE;
    int lim = min(TILE, n - base);
    int nw = (lim + 63) >> 6;
    for (int j = threadIdx.x; j < nw; j += BLOCK) swords[j] = bitmask[(base >> 6) + j];
    __syncthreads();
    if (threadIdx.x == 0) {
        int acc = 0;
        for (int k = 0; k < nw; k++) { wpre[k] = acc; acc += __popcll(swords[k]); }
        int s0 = find_seg(rs, n_seg, base);
        int s1 = find_seg(rs, n_seg, base + lim - 1);
        shead[0] = (s1 != s0) ? rs[s0 + 1] : 0x7FFFFFFF;
        shead[1] = s0;
        shead[2] = s1;
        shead[3] = acc;
        int a2 = 0;   // exclusive chunk prefix (serial over <=NCMAX entries)
        for (int c = 0; c < nchunk; c++) { int t = chq[c]; chq[c] = a2; a2 += t; }
    }
    __syncthreads();
    int lane = threadIdx.x & 63, wv = threadIdx.x >> 6;
    {
        int s0 = shead[1], s1 = shead[2];
        if (wv == 0) {
            int r = wave_prefix_at(base, chq, block_counts, bitmask, lane);
            if (lane == 0) shead[4] = r;                       // block offset
        } else if (wv == 1) {
            unsigned int u = (unsigned int)(seg_packed[s0] & 0xFFFFFFFFu);
            int r = (u >= (unsigned int)n) ? M
                    : wave_prefix_at((int)u, chq, block_counts, bitmask, lane);
            if (lane == 0) shead[5] = r;                       // rep0
        } else if (wv == 2) {
            unsigned int u = (unsigned int)(seg_packed[s1] & 0xFFFFFFFFu);
            int r = (u >= (unsigned int)n) ? M
                    : wave_prefix_at((int)u, chq, block_counts, bitmask, lane);
            if (lane == 0) shead[6] = r;                       // rep1
        } else {
            // newrs boundaries owned by this block (each rs[q] < n lies in
            // exactly one block's range); q = n_seg handled by last block.
            for (int q = 0; q < n_seg; q++) {
                int u = rs[q];
                if (u >= base && u < base + lim) {
                    int r = wave_prefix_at(u, chq, block_counts, bitmask, lane);
                    if (lane == 0) newrs_out[q] = r;
                }
            }
            if (blockIdx.x == nb - 1 && lane == 0) newrs_out[n_seg] = M;
        }
    }
    __syncthreads();
    int bval = shead[0], tot = shead[3], bo = shead[4];
    int rep0 = shead[5], rep1 = shead[6];
    // phases
    int st_b = (int)((4 - ((((uintptr_t)(back_out + base)) >> 2) & 3)) & 3);
    if (st_b > lim) st_b = lim;
    int st_s = (int)((4 - ((((uintptr_t)(sel_out + bo)) >> 2) & 3)) & 3);
    if (st_s > tot) st_s = tot;
    int selpad = 4 - st_s;          // skel slot = (pos - bo) + selpad; first aligned slot = 4

    // main: full int4 groups of back_out; also stage kept indices into skel
    int ngroups = (lim - st_b) >> 2;
    for (int g = threadIdx.x; g < ngroups; g += BLOCK) {
        int j0 = st_b + 4 * g;
        int vals[4];
        #pragma unroll
        for (int k = 0; k < 4; k++) {
            int j = j0 + k;
            int widx = j >> 6, r = j & 63;
            u64 w = swords[widx];
            int i = base + j;
            if ((w >> r) & 1) {
                int pos = bo + wpre[widx] + __popcll(w & ((1ull << r) - 1));
                vals[k] = pos;
                skel[pos - bo + selpad] = i;
            } else {
                vals[k] = (i >= bval) ? rep1 : rep0;
            }
        }
        *(int4*)(back_out + base + j0) = make_int4(vals[0], vals[1], vals[2], vals[3]);
    }
    // edges of back region (<=3 head, <=3 tail)
    for (int j = threadIdx.x; j < st_b; j += BLOCK) {
        int widx = j >> 6, r = j & 63;
        u64 w = swords[widx];
        int i = base + j, val;
        if ((w >> r) & 1) {
            int pos = bo + wpre[widx] + __popcll(w & ((1ull << r) - 1));
            val = pos;
            skel[pos - bo + selpad] = i;
        } else val = (i >= bval) ? rep1 : rep0;
        back_out[i] = val;
    }
    for (int j = st_b + 4 * ngroups + threadIdx.x; j < lim; j += BLOCK) {
        int widx = j >> 6, r = j & 63;
        u64 w = swords[widx];
        int i = base + j, val;
        if ((w >> r) & 1) {
            int pos = bo + wpre[widx] + __popcll(w & ((1ull << r) - 1));
            val = pos;
            skel[pos - bo + selpad] = i;
        } else val = (i >= bval) ? rep1 : rep0;
        back_out[i] = val;
    }
    __syncthreads();
    // sel_out: aligned int4 stores fed by aligned ds_read_b128
    int nvg = (tot - st_s) >> 2;
    for (int g = threadIdx.x; g < nvg; g += BLOCK) {
        int4 v = *(const int4*)&skel[4 + 4 * g];
        *(int4*)(sel_out + bo + st_s + 4 * g) = v;
    }
    for (int j = threadIdx.x; j < st_s; j += BLOCK) sel_out[bo + j] = skel[j + selpad];
    for (int j = st_s + 4 * nvg + threadIdx.x; j < tot; j += BLOCK) sel_out[bo + j] = skel[j + selpad];
}

extern "C" void kernel_launch(void* const* d_in, const int* in_sizes, int n_in,
                              void* d_out, int out_size, void* d_ws, size_t ws_size,
                              hipStream_t stream) {
    const float* score = (const float*)d_in[0];
    const int* row_splits = (const int*)d_in[1];
    int n = in_sizes[0];
    int n_seg = in_sizes[1] - 1;
    int M = out_size - (n_seg + 1) - n;
    int nb = (n + TILE - 1) / TILE;
    int nwords = (n + 63) / 64;
    int nchunk = (nb + CHUNK - 1) / CHUNK;

    u64* seg_packed   = (u64*)d_ws;                      // MAXSEG u64  (init 0xFF)
    int* chunk_sums   = (int*)(seg_packed + MAXSEG);     // nchunk int  (init -1)
    uintptr_t pv_addr = (uintptr_t)(chunk_sums + nchunk);
    pv_addr = (pv_addr + 7) & ~(uintptr_t)7;
    u64* partial_val  = (u64*)pv_addr;                   // 2*nb u64
    int* partial_seg  = (int*)(partial_val + 2 * nb);    // 2*nb int
    int* block_counts = partial_seg + 2 * nb;            // nb int
    uintptr_t bm_addr = (uintptr_t)(block_counts + nb);
    bm_addr = (bm_addr + 7) & ~(uintptr_t)7;
    u64* bitmask      = (u64*)bm_addr;                   // nwords u64

    int* out = (int*)d_out;
    int* sel_out   = out;
    int* newrs_out = out + M;
    int* back_out  = out + M + (n_seg + 1);

    // single tiny init: seg_packed=~0 (atomicMin identity), chunk_sums=-1
    // (-1-encoded accumulators)
    size_t init_bytes = (size_t)((char*)(chunk_sums + nchunk) - (char*)d_ws);
    hipMemsetAsync(d_ws, 0xFF, init_bytes, stream);
    hipLaunchKernelGGL(k_pass1, dim3(nb), dim3(BLOCK), 0, stream,
                       score, row_splits, n_seg, n, nwords,
                       partial_val, partial_seg, bitmask, block_counts,
                       seg_packed, chunk_sums);
    hipLaunchKernelGGL(k_segfix, dim3(n_seg), dim3(BLOCK), 0, stream,
                       score, row_splits, n,
                       partial_val, partial_seg, seg_packed, bitmask,
                       block_counts, chunk_sums);
    hipLaunchKernelGGL(k_output, dim3(nb), dim3(BLOCK), 0, stream,
                       row_splits, n_seg, n, nb, nchunk, M,
                       seg_packed, bitmask, block_counts, chunk_sums,
                       sel_out, back_out, newrs_out);
}

// Round 4
// 180.472 us; speedup vs baseline: 2.0859x; 1.1391x over previous
//
#include <hip/hip_runtime.h>
#include <stdint.h>

#define BLOCK 256
#define ITEMS 8
#define TILE (BLOCK * ITEMS)   // 2048 elements per block
#define WPB (TILE / 64)        // 32 bitmask words per block
#define MAXSEG 64
#define CHUNK 64               // tiles per count-chunk (for per-block self-scan)
#define NCMAX 128              // supports nb <= 8192 (n <= 16.7M)
#define SEGSTRIDE 16           // u64s per seg_packed slot = 128B (own cache line)
#define CHSTRIDE 32            // ints per chunk_sums slot = 128B (own cache line)
#define THRESH 0.1f

typedef unsigned long long u64;

__device__ __forceinline__ int find_seg(const int* rs, int n_seg, int i) {
    // largest s with rs[s] <= i
    int lo = 0, hi = n_seg;
    while (hi - lo > 1) {
        int mid = (lo + hi) >> 1;
        if (rs[mid] <= i) lo = mid; else hi = mid;
    }
    return lo;
}

// Wave-cooperative global keep-prefix at element index idx.
// prefix = chq[chunk] (exclusive chunk prefix, LDS) + counts of tiles before
// idx's tile within the chunk (<=63 loads) + popcounts of this tile's words
// before idx (<=31 loads) + partial word. Result valid on lane 0.
__device__ __forceinline__ int wave_prefix_at(int idx, const int* chq,
        const int* __restrict__ bc, const u64* __restrict__ bm, int lane) {
    int t = idx / TILE;
    int c = t / CHUNK;
    int v = 0;
    int j = c * CHUNK + lane;
    if (j < t) v += bc[j];
    int wq = idx >> 6;
    int w = t * WPB + lane;
    if (lane < WPB && w < wq) v += __popcll(bm[w]);
    if (lane == 0 && (idx & 63)) v += __popcll(bm[wq] & ((1ull << (idx & 63)) - 1));
    for (int o = 32; o > 0; o >>= 1) v += __shfl_down(v, o, 64);
    return chq[c] + v;
}

// Pass 1: single read of score producing
//   - threshold keep-bitmask (s > THRESH)  [min-tied bits fixed up in k_segfix]
//   - per-block keep counts + per-chunk sums (chunk_sums, -1-encoded, atomic,
//     PADDED one cache line per chunk: dense layout serialized ~1500 atomics
//     per 128B line at the memory-side atomic unit — the Round-3 regression)
//   - per-block packed (min_bits<<32 | idx) partials, <=2 segments per block
//   - per-segment global min via device-scope atomicMin (padded likewise).
//   NO fences — cross-block plain-store visibility is carried by kernel
//   boundaries only (Round-1's per-block __threadfence = agent-scope L2
//   writeback per block, ~200us stall).
__global__ __launch_bounds__(BLOCK) void k_pass1(const float* __restrict__ score,
        const int* __restrict__ row_splits, int n_seg, int n, int nwords,
        u64* __restrict__ partial_val, int* __restrict__ partial_seg,
        u64* __restrict__ bitmask, int* __restrict__ block_counts,
        u64* __restrict__ seg_packed, int* __restrict__ chunk_sums) {
    __shared__ int rs[MAXSEG + 1];
    __shared__ u64 wval[8];
    __shared__ int wseg[8];
    __shared__ int wsum[4];
    for (int j = threadIdx.x; j <= n_seg; j += BLOCK) rs[j] = row_splits[j];
    __syncthreads();
    int lane = threadIdx.x & 63, wv = threadIdx.x >> 6;
    int wbase = blockIdx.x * TILE + wv * 512;
    u64 m0 = ~0ull, m1 = ~0ull;
    int sf = -1, sl = -1, cnt = 0;
    if (wbase < n) {   // wave-uniform
        int wend = min(n, wbase + 512) - 1;
        sf = find_seg(rs, n_seg, wbase);
        sl = find_seg(rs, n_seg, wend);
        int bval = (sl != sf) ? rs[sf + 1] : 0x7FFFFFFF;
        int tbase = wbase + lane * 8;
        unsigned int kbyte = 0;
        if (tbase < n) {
            float v[8];
            if (tbase + 8 <= n) {
                float4 f0 = *(const float4*)(score + tbase);
                float4 f1 = *(const float4*)(score + tbase + 4);
                v[0]=f0.x; v[1]=f0.y; v[2]=f0.z; v[3]=f0.w;
                v[4]=f1.x; v[5]=f1.y; v[6]=f1.z; v[7]=f1.w;
            } else {
                for (int j = 0; j < 8; j++) v[j] = (tbase + j < n) ? score[tbase + j] : 1.0f;
            }
            #pragma unroll
            for (int j = 0; j < 8; j++) {
                int i = tbase + j;
                if (i < n) {
                    u64 p = ((u64)__float_as_uint(v[j]) << 32) | (unsigned int)i;
                    if (i < bval) m0 = min(m0, p); else m1 = min(m1, p);
                    if (v[j] > THRESH) kbyte |= 1u << j;
                }
            }
            cnt = __popc(kbyte);
        }
        // assemble 64-bit words within groups of 8 lanes
        u64 acc = ((u64)kbyte) << (8 * (lane & 7));
        acc |= __shfl_xor((unsigned long long)acc, 1, 64);
        acc |= __shfl_xor((unsigned long long)acc, 2, 64);
        acc |= __shfl_xor((unsigned long long)acc, 4, 64);
        int src = (lane < 8) ? (8 * lane) : lane;
        u64 myword = __shfl((unsigned long long)acc, src, 64);
        for (int o = 32; o > 0; o >>= 1) {
            m0 = min(m0, (u64)__shfl_down((unsigned long long)m0, o, 64));
            m1 = min(m1, (u64)__shfl_down((unsigned long long)m1, o, 64));
            cnt += __shfl_down(cnt, o, 64);
        }
        if (lane < 8) {
            int w = (wbase >> 6) + lane;
            if (w < nwords) bitmask[w] = myword;
        }
    }
    if (lane == 0) {
        wval[2 * wv] = m0;     wseg[2 * wv] = sf;
        wval[2 * wv + 1] = m1; wseg[2 * wv + 1] = (sl != sf) ? sl : -1;
        wsum[wv] = (wbase < n) ? cnt : 0;
    }
    __syncthreads();
    if (threadIdx.x == 0) {
        int base = blockIdx.x * TILE;
        int endi = min(n, base + TILE) - 1;
        int s0 = find_seg(rs, n_seg, base);
        int s1 = find_seg(rs, n_seg, endi);
        u64 o0 = ~0ull, o1 = ~0ull;
        for (int k = 0; k < 8; k++) {
            if (wseg[k] == s0) o0 = min(o0, wval[k]);
            else if (wseg[k] == s1) o1 = min(o1, wval[k]);
        }
        partial_val[2 * blockIdx.x] = o0;
        partial_seg[2 * blockIdx.x] = s0;
        partial_val[2 * blockIdx.x + 1] = o1;
        partial_seg[2 * blockIdx.x + 1] = (s1 != s0) ? s1 : -1;
        int bc = wsum[0] + wsum[1] + wsum[2] + wsum[3];
        block_counts[blockIdx.x] = bc;
        // coherent device-scope atomics, one 128B line per target (no fences)
        atomicMin(&seg_packed[SEGSTRIDE * s0], o0);
        if (s1 != s0) atomicMin(&seg_packed[SEGSTRIDE * s1], o1);
        atomicAdd(&chunk_sums[CHSTRIDE * (blockIdx.x / CHUNK)], bc);
    }
}

// Pass 2: one block PER SEGMENT. seg min is already reduced in seg_packed
// (pass1's atomicMin; visible across the kernel boundary). If segmin <= THRESH,
// set keep bits for min-tied elements (re-reads only the matched ~2048-elem
// tiles) and bump block_counts + chunk_sums (few ops, no contention).
__global__ __launch_bounds__(BLOCK) void k_segfix(const float* __restrict__ score,
        const int* __restrict__ row_splits, int n,
        const u64* __restrict__ partial_val, const int* __restrict__ partial_seg,
        const u64* __restrict__ seg_packed, u64* __restrict__ bitmask,
        int* __restrict__ block_counts, int* __restrict__ chunk_sums) {
    __shared__ int nmatch;
    __shared__ int mlist[64];
    int s = blockIdx.x;
    int lo = row_splits[s], hi = row_splits[s + 1];
    int lane = threadIdx.x & 63;
    if (threadIdx.x == 0) nmatch = 0;
    __syncthreads();
    if (hi <= lo) return;
    u64 sp = seg_packed[SEGSTRIDE * s];
    if (sp == ~0ull) return;
    unsigned int smb = (unsigned int)(sp >> 32);
    if (__uint_as_float(smb) > THRESH) return;   // threshold bit already covers min elems
    int e0 = 2 * (lo / TILE);
    int e1 = 2 * ((hi - 1) / TILE) + 1;
    for (int e = e0 + threadIdx.x; e <= e1; e += BLOCK) {
        if (partial_seg[e] == s && (unsigned int)(partial_val[e] >> 32) == smb) {
            int k = atomicAdd(&nmatch, 1);   // LDS atomic, rare
            if (k < 64) mlist[k] = e >> 1;
        }
    }
    __syncthreads();
    int nm = min(nmatch, 64);
    for (int k = 0; k < nm; k++) {
        int b = mlist[k];
        int rlo = max(b * TILE, lo);
        int rhi = min(min((b + 1) * TILE, n), hi);
        int c = 0;
        for (int i = rlo + threadIdx.x; i < rhi; i += BLOCK) {
            if (__float_as_uint(score[i]) == smb) {
                atomicOr(&bitmask[i >> 6], 1ull << (i & 63));
                c++;
            }
        }
        for (int o = 32; o > 0; o >>= 1) c += __shfl_down(c, o, 64);
        if (lane == 0 && c) {
            atomicAdd(&block_counts[b], c);
            atomicAdd(&chunk_sums[CHSTRIDE * (b / CHUNK)], c);
        }
    }
}

// Pass 3 (fused scanq + output): each block derives its own global offset,
// its segments' rep positions, and any newrs boundary it owns, via
// wave-cooperative prefix queries over chunk_sums/block_counts/bitmask
// (all L2-resident). Prologue parallelized: wave 0 shfl-scans the chunk sums
// (2/lane) while thread 64 computes wpre/shead — no thread0 serial chain.
// Then the output body: back values in registers for 4 phase-aligned
// positions -> dwordx4 stores; sel indices staged in LDS with slot offset so
// vector reads are aligned ds_read_b128. Assumes <=1 segment boundary per
// 2048-elem block (seg len >> 2048 here) and nchunk <= NCMAX.
__global__ __launch_bounds__(BLOCK) void k_output(const int* __restrict__ row_splits,
        int n_seg, int n, int nb, int nchunk, int M,
        const u64* __restrict__ seg_packed, const u64* __restrict__ bitmask,
        const int* __restrict__ block_counts, const int* __restrict__ chunk_sums,
        int* __restrict__ sel_out, int* __restrict__ back_out,
        int* __restrict__ newrs_out) {
    __shared__ int rs[MAXSEG + 1];
    __shared__ u64 swords[WPB];
    __shared__ int wpre[WPB];
    __shared__ int shead[8];   // bval, s0, s1, tot, bo, rep0, rep1
    __shared__ int chq[NCMAX];
    __shared__ alignas(16) int skel[TILE + 8];
    for (int j = threadIdx.x; j <= n_seg; j += BLOCK) rs[j] = row_splits[j];
    int base = blockIdx.x * TILE;
    int lim = min(TILE, n - base);
    int nw = (lim + 63) >> 6;
    for (int j = threadIdx.x; j < nw; j += BLOCK) swords[j] = bitmask[(base >> 6) + j];
    __syncthreads();
    int lane = threadIdx.x & 63, wv = threadIdx.x >> 6;
    if (wv == 0) {
        // exclusive prefix over (chunk_sums[c]+1), 2 chunks per lane
        int c0 = 2 * lane, c1 = 2 * lane + 1;
        int a = (c0 < nchunk) ? chunk_sums[CHSTRIDE * c0] + 1 : 0;   // decode -1 init
        int b2 = (c1 < nchunk) ? chunk_sums[CHSTRIDE * c1] + 1 : 0;
        int ps = a + b2;
        int incl = ps;
        for (int o = 1; o < 64; o <<= 1) {
            int t = __shfl_up(incl, o, 64);
            if (lane >= o) incl += t;
        }
        int excl = incl - ps;
        if (c0 < nchunk) chq[c0] = excl;
        if (c1 < nchunk) chq[c1] = excl + a;
    } else if (threadIdx.x == 64) {
        int acc = 0;
        for (int k = 0; k < nw; k++) { wpre[k] = acc; acc += __popcll(swords[k]); }
        int s0 = find_seg(rs, n_seg, base);
        int s1 = find_seg(rs, n_seg, base + lim - 1);
        shead[0] = (s1 != s0) ? rs[s0 + 1] : 0x7FFFFFFF;
        shead[1] = s0;
        shead[2] = s1;
        shead[3] = acc;
    }
    __syncthreads();
    {
        int s0 = shead[1], s1 = shead[2];
        if (wv == 0) {
            int r = wave_prefix_at(base, chq, block_counts, bitmask, lane);
            if (lane == 0) shead[4] = r;                       // block offset
        } else if (wv == 1) {
            unsigned int u = (unsigned int)(seg_packed[SEGSTRIDE * s0] & 0xFFFFFFFFu);
            int r = (u >= (unsigned int)n) ? M
                    : wave_prefix_at((int)u, chq, block_counts, bitmask, lane);
            if (lane == 0) shead[5] = r;                       // rep0
        } else if (wv == 2) {
            unsigned int u = (unsigned int)(seg_packed[SEGSTRIDE * s1] & 0xFFFFFFFFu);
            int r = (u >= (unsigned int)n) ? M
                    : wave_prefix_at((int)u, chq, block_counts, bitmask, lane);
            if (lane == 0) shead[6] = r;                       // rep1
        } else {
            // newrs boundaries owned by this block (each rs[q] < n lies in
            // exactly one block's range); q = n_seg handled by last block.
            for (int q = 0; q < n_seg; q++) {
                int u = rs[q];
                if (u >= base && u < base + lim) {
                    int r = wave_prefix_at(u, chq, block_counts, bitmask, lane);
                    if (lane == 0) newrs_out[q] = r;
                }
            }
            if (blockIdx.x == nb - 1 && lane == 0) newrs_out[n_seg] = M;
        }
    }
    __syncthreads();
    int bval = shead[0], tot = shead[3], bo = shead[4];
    int rep0 = shead[5], rep1 = shead[6];
    // phases
    int st_b = (int)((4 - ((((uintptr_t)(back_out + base)) >> 2) & 3)) & 3);
    if (st_b > lim) st_b = lim;
    int st_s = (int)((4 - ((((uintptr_t)(sel_out + bo)) >> 2) & 3)) & 3);
    if (st_s > tot) st_s = tot;
    int selpad = 4 - st_s;          // skel slot = (pos - bo) + selpad; first aligned slot = 4

    // main: full int4 groups of back_out; also stage kept indices into skel
    int ngroups = (lim - st_b) >> 2;
    for (int g = threadIdx.x; g < ngroups; g += BLOCK) {
        int j0 = st_b + 4 * g;
        int vals[4];
        #pragma unroll
        for (int k = 0; k < 4; k++) {
            int j = j0 + k;
            int widx = j >> 6, r = j & 63;
            u64 w = swords[widx];
            int i = base + j;
            if ((w >> r) & 1) {
                int pos = bo + wpre[widx] + __popcll(w & ((1ull << r) - 1));
                vals[k] = pos;
                skel[pos - bo + selpad] = i;
            } else {
                vals[k] = (i >= bval) ? rep1 : rep0;
            }
        }
        *(int4*)(back_out + base + j0) = make_int4(vals[0], vals[1], vals[2], vals[3]);
    }
    // edges of back region (<=3 head, <=3 tail)
    for (int j = threadIdx.x; j < st_b; j += BLOCK) {
        int widx = j >> 6, r = j & 63;
        u64 w = swords[widx];
        int i = base + j, val;
        if ((w >> r) & 1) {
            int pos = bo + wpre[widx] + __popcll(w & ((1ull << r) - 1));
            val = pos;
            skel[pos - bo + selpad] = i;
        } else val = (i >= bval) ? rep1 : rep0;
        back_out[i] = val;
    }
    for (int j = st_b + 4 * ngroups + threadIdx.x; j < lim; j += BLOCK) {
        int widx = j >> 6, r = j & 63;
        u64 w = swords[widx];
        int i = base + j, val;
        if ((w >> r) & 1) {
            int pos = bo + wpre[widx] + __popcll(w & ((1ull << r) - 1));
            val = pos;
            skel[pos - bo + selpad] = i;
        } else val = (i >= bval) ? rep1 : rep0;
        back_out[i] = val;
    }
    __syncthreads();
    // sel_out: aligned int4 stores fed by aligned ds_read_b128
    int nvg = (tot - st_s) >> 2;
    for (int g = threadIdx.x; g < nvg; g += BLOCK) {
        int4 v = *(const int4*)&skel[4 + 4 * g];
        *(int4*)(sel_out + bo + st_s + 4 * g) = v;
    }
    for (int j = threadIdx.x; j < st_s; j += BLOCK) sel_out[bo + j] = skel[j + selpad];
    for (int j = st_s + 4 * nvg + threadIdx.x; j < tot; j += BLOCK) sel_out[bo + j] = skel[j + selpad];
}

extern "C" void kernel_launch(void* const* d_in, const int* in_sizes, int n_in,
                              void* d_out, int out_size, void* d_ws, size_t ws_size,
                              hipStream_t stream) {
    const float* score = (const float*)d_in[0];
    const int* row_splits = (const int*)d_in[1];
    int n = in_sizes[0];
    int n_seg = in_sizes[1] - 1;
    int M = out_size - (n_seg + 1) - n;
    int nb = (n + TILE - 1) / TILE;
    int nwords = (n + 63) / 64;
    int nchunk = (nb + CHUNK - 1) / CHUNK;

    u64* seg_packed   = (u64*)d_ws;                      // MAXSEG*SEGSTRIDE u64 (init 0xFF)
    int* chunk_sums   = (int*)(seg_packed + MAXSEG * SEGSTRIDE); // nchunk*CHSTRIDE int (init -1)
    uintptr_t pv_addr = (uintptr_t)(chunk_sums + (size_t)nchunk * CHSTRIDE);
    pv_addr = (pv_addr + 7) & ~(uintptr_t)7;
    u64* partial_val  = (u64*)pv_addr;                   // 2*nb u64
    int* partial_seg  = (int*)(partial_val + 2 * nb);    // 2*nb int
    int* block_counts = partial_seg + 2 * nb;            // nb int
    uintptr_t bm_addr = (uintptr_t)(block_counts + nb);
    bm_addr = (bm_addr + 7) & ~(uintptr_t)7;
    u64* bitmask      = (u64*)bm_addr;                   // nwords u64

    int* out = (int*)d_out;
    int* sel_out   = out;
    int* newrs_out = out + M;
    int* back_out  = out + M + (n_seg + 1);

    // single tiny init (~20KB): seg_packed=~0 (atomicMin identity),
    // chunk_sums=-1 (-1-encoded accumulators); padding bytes don't matter
    size_t init_bytes = (size_t)((char*)(chunk_sums + (size_t)nchunk * CHSTRIDE) - (char*)d_ws);
    hipMemsetAsync(d_ws, 0xFF, init_bytes, stream);
    hipLaunchKernelGGL(k_pass1, dim3(nb), dim3(BLOCK), 0, stream,
                       score, row_splits, n_seg, n, nwords,
                       partial_val, partial_seg, bitmask, block_counts,
                       seg_packed, chunk_sums);
    hipLaunchKernelGGL(k_segfix, dim3(n_seg), dim3(BLOCK), 0, stream,
                       score, row_splits, n,
                       partial_val, partial_seg, seg_packed, bitmask,
                       block_counts, chunk_sums);
    hipLaunchKernelGGL(k_output, dim3(nb), dim3(BLOCK), 0, stream,
                       row_splits, n_seg, n, nb, nchunk, M,
                       seg_packed, bitmask, block_counts, chunk_sums,
                       sel_out, back_out, newrs_out);
}